// Round 4
// baseline (472.183 us; speedup 1.0000x reference)
//
#include <hip/hip_runtime.h>

#define AS1 __attribute__((address_space(1)))
#define AS3 __attribute__((address_space(3)))

typedef __attribute__((ext_vector_type(8))) short short8;        // 8 bf16 raw (4 VGPRs) — MFMA A/B frag
typedef __attribute__((ext_vector_type(4))) float floatx4;       // MFMA C/D frag
typedef __attribute__((ext_vector_type(8))) unsigned short u16x8;
typedef __attribute__((ext_vector_type(4))) unsigned short u16x4;
typedef __attribute__((ext_vector_type(4))) float f32x4;

#define M_DIM 8192   // B*S = 4*2048
#define K_DIM 4096   // IN_F
#define N_DIM 4096   // OUT_F
#define NB    512    // blocks along in/out feature dims
// BLK = 8, rfft comps: f0(real), f1,f2,f3(complex), f4(real)

#define SQ2H 0.70710678118654752f

// Xfreq plane offsets (bf16 elements), total 33,554,432 elems = 64 MB
#define P0_OFF 0           // [8192][512]  f0 (real)
#define P1_OFF 4194304     // [8192][1024] f1 (re,im interleaved k=2i,2i+1)
#define P2_OFF 12582912    // [8192][1024] f2
#define P3_OFF 20971520    // [8192][1024] f3
#define P4_OFF 29360128    // [8192][512]  f4 (real)
// Wfreq plane offsets (bf16 elements), total 3,670,016 elems = 7 MB
#define Q0_OFF 0           // [512][512]
#define Q1_OFF 262144      // [1024][1024] rows 0..511: (B1r,-B1i); rows 512..1023: (B1i,B1r)
#define Q2_OFF 1310720
#define Q3_OFF 2359296
#define Q4_OFF 3407872     // [512][512]

// fp32 -> bf16 raw bits, round-to-nearest-even (finite inputs only).
static __device__ __forceinline__ unsigned short f32_to_bf16(float f) {
  union { float f; unsigned int u; } v;
  v.f = f;
  return (unsigned short)((v.u + 0x7FFFu + ((v.u >> 16) & 1u)) >> 16);
}

// length-8 real FFT comps from 8 reals
struct F8 { float a0, a4, r1, i1, r2, i2, r3, i3; };
static __device__ __forceinline__ F8 rfft8(const float* x) {
  F8 o;
  o.a0 = x[0]+x[1]+x[2]+x[3]+x[4]+x[5]+x[6]+x[7];
  o.a4 = x[0]-x[1]+x[2]-x[3]+x[4]-x[5]+x[6]-x[7];
  const float d1 = x[1]-x[3]-x[5]+x[7];   // for r1/r3
  const float s1 = x[1]+x[3]-x[5]-x[7];   // for i1/i3
  o.r1 = x[0]-x[4] + SQ2H*d1;
  o.i1 = -(SQ2H*s1 + x[2]-x[6]);
  o.r2 = x[0]-x[2]+x[4]-x[6];
  o.i2 = -(x[1]-x[3]+x[5]-x[7]);
  o.r3 = x[0]-x[4] - SQ2H*d1;
  o.i3 = -(SQ2H*s1 - x[2]+x[6]);
  return o;
}

// ===========================================================================
// FREQ PATH, 2 kernels: prep (w+x transforms fused) -> gemm_fused (5-plane
// GEMM + in-register irfft + bias + fp32 store; OF buffer eliminated)
// ===========================================================================

// blocks [0,1024): circ -> WF.  blocks [1024,1024+4096): x -> XF (LDS-bounce).
__global__ __launch_bounds__(256) void prep_kernel(
    const float* __restrict__ x, const float* __restrict__ circ,
    unsigned short* __restrict__ XF, unsigned short* __restrict__ WF)
{
  __shared__ alignas(16) float lds[8192];          // 32 KB (x-branch only)
  const int t = threadIdx.x;

  if (blockIdx.x < 1024) {
    // ---- wtransform: circ (fp32 (512,512,8)) -> Wfreq planes (bf16) ----
    const int tid = blockIdx.x * 256 + t;          // 0 .. 512*512-1
    const int n = tid >> 9;   // output block
    const int i = tid & 511;  // input block
    float v[8];
    *reinterpret_cast<f32x4*>(v)     = *reinterpret_cast<const f32x4*>(circ + (size_t)tid * 8);
    *reinterpret_cast<f32x4*>(v + 4) = *reinterpret_cast<const f32x4*>(circ + (size_t)tid * 8 + 4);
    F8 f = rfft8(v);
    WF[Q0_OFF + (size_t)n * 512 + i] = f32_to_bf16(f.a0);
    WF[Q4_OFF + (size_t)n * 512 + i] = f32_to_bf16(f.a4);
    unsigned int q1or = (unsigned int)f32_to_bf16(f.r1) | ((unsigned int)f32_to_bf16(-f.i1) << 16);
    unsigned int q1oi = (unsigned int)f32_to_bf16(f.i1) | ((unsigned int)f32_to_bf16(f.r1) << 16);
    unsigned int q2or = (unsigned int)f32_to_bf16(f.r2) | ((unsigned int)f32_to_bf16(-f.i2) << 16);
    unsigned int q2oi = (unsigned int)f32_to_bf16(f.i2) | ((unsigned int)f32_to_bf16(f.r2) << 16);
    unsigned int q3or = (unsigned int)f32_to_bf16(f.r3) | ((unsigned int)f32_to_bf16(-f.i3) << 16);
    unsigned int q3oi = (unsigned int)f32_to_bf16(f.i3) | ((unsigned int)f32_to_bf16(f.r3) << 16);
    *reinterpret_cast<unsigned int*>(WF + Q1_OFF + (size_t)n * 1024 + 2 * i)         = q1or;
    *reinterpret_cast<unsigned int*>(WF + Q1_OFF + (size_t)(512 + n) * 1024 + 2 * i) = q1oi;
    *reinterpret_cast<unsigned int*>(WF + Q2_OFF + (size_t)n * 1024 + 2 * i)         = q2or;
    *reinterpret_cast<unsigned int*>(WF + Q2_OFF + (size_t)(512 + n) * 1024 + 2 * i) = q2oi;
    *reinterpret_cast<unsigned int*>(WF + Q3_OFF + (size_t)n * 1024 + 2 * i)         = q3or;
    *reinterpret_cast<unsigned int*>(WF + Q3_OFF + (size_t)(512 + n) * 1024 + 2 * i) = q3oi;
    return;
  }

  // ---- xtransform: x (fp32 (8192,4096)) -> Xfreq planes, LDS-bounce ----
  const int bx = blockIdx.x - 1024;                // 0..4095
  const int m0 = bx * 2;
  const float* src = x + (size_t)m0 * 4096;

#pragma unroll
  for (int s = 0; s < 8; ++s) {
    const int u  = s * 256 + t;                    // 16B-unit 0..2047
    const int pu = u ^ ((u >> 3) & 7);
    *reinterpret_cast<f32x4*>(lds + pu * 4) =
        *reinterpret_cast<const f32x4*>(src + (size_t)u * 4);
  }
  __syncthreads();

  const int r  = t >> 7;                           // local row 0/1
  const int i4 = t & 127;                          // input blocks i4*4 .. +3
  float v[32];
#pragma unroll
  for (int p = 0; p < 8; ++p) {
    const int u  = r * 1024 + i4 * 8 + p;
    const int pu = u ^ ((u >> 3) & 7);
    *reinterpret_cast<f32x4*>(v + p * 4) = *reinterpret_cast<const f32x4*>(lds + pu * 4);
  }

  const int m = m0 + r;
  u16x4 p0, p4;
  u16x8 p1, p2, p3;
#pragma unroll
  for (int g = 0; g < 4; ++g) {
    F8 f = rfft8(v + g * 8);
    p0[g] = f32_to_bf16(f.a0);
    p4[g] = f32_to_bf16(f.a4);
    p1[2*g] = f32_to_bf16(f.r1); p1[2*g+1] = f32_to_bf16(f.i1);
    p2[2*g] = f32_to_bf16(f.r2); p2[2*g+1] = f32_to_bf16(f.i2);
    p3[2*g] = f32_to_bf16(f.r3); p3[2*g+1] = f32_to_bf16(f.i3);
  }
  *reinterpret_cast<u16x4*>(XF + P0_OFF + (size_t)m * 512 + i4 * 4) = p0;
  *reinterpret_cast<u16x4*>(XF + P4_OFF + (size_t)m * 512 + i4 * 4) = p4;
  *reinterpret_cast<u16x8*>(XF + P1_OFF + (size_t)m * 1024 + i4 * 8) = p1;
  *reinterpret_cast<u16x8*>(XF + P2_OFF + (size_t)m * 1024 + i4 * 8) = p2;
  *reinterpret_cast<u16x8*>(XF + P3_OFF + (size_t)m * 1024 + i4 * 8) = p3;
}

// One K-step-64 plane loop over KZ, accumulating real (and optionally imag)
// components. Both-sides XOR swizzle on 16B-unit bit 2 keyed by LDS row
// parity: staging pre-swizzles the GLOBAL source k-offset (gload_lds dest
// stays linear, rule: wave-uniform base + lane*16), reads apply the same XOR.
#define PLANE_LOOP(KZ, APL, QPL, ACC_R, ACC_I, CPLX)                          \
  for (int k0 = 0; k0 < (KZ); k0 += 64) {                                     \
    _Pragma("unroll")                                                         \
    for (int j_ = 0; j_ < 4; ++j_) {                                          \
      const int c_   = j_ * 256 + tid;                                        \
      const int row_ = c_ >> 3;                                               \
      const int lu_  = (c_ & 7) ^ ((row_ & 1) << 2);                          \
      const unsigned short* ga_ = (APL) + (size_t)(m0 + row_) * (KZ) + k0 + lu_ * 8; \
      __builtin_amdgcn_global_load_lds((AS1 void*)ga_, (AS3 void*)(As + c_ * 8), 16, 0, 0); \
    }                                                                         \
    {                                                                         \
      const int r0_  = tid >> 3;                                              \
      const int lu0_ = (tid & 7) ^ ((r0_ & 1) << 2);                          \
      const unsigned short* gb0_ = (QPL) + (size_t)(n0b + r0_) * (KZ) + k0 + lu0_ * 8; \
      __builtin_amdgcn_global_load_lds((AS1 void*)gb0_, (AS3 void*)(Bs + tid * 8), 16, 0, 0); \
      if (CPLX) {                                                             \
        const int c1_  = 256 + tid;                                           \
        const int rl_  = c1_ >> 3;                /* 32..63 */                \
        const int lu1_ = (c1_ & 7) ^ ((rl_ & 1) << 2);                        \
        const unsigned short* gb1_ = (QPL) + (size_t)(512 + n0b + (rl_ - 32)) * (KZ) + k0 + lu1_ * 8; \
        __builtin_amdgcn_global_load_lds((AS1 void*)gb1_, (AS3 void*)(Bs + c1_ * 8), 16, 0, 0); \
      }                                                                       \
    }                                                                         \
    __syncthreads();                                                          \
    _Pragma("unroll")                                                         \
    for (int s_ = 0; s_ < 2; ++s_) {                                          \
      const int u_ = (s_ * 4 + quad) ^ par4;                                  \
      short8 af_[4];                                                          \
      _Pragma("unroll")                                                       \
      for (int mi_ = 0; mi_ < 4; ++mi_)                                       \
        af_[mi_] = *reinterpret_cast<const short8*>(As + (wm * 64 + mi_ * 16 + l15) * 64 + u_ * 8); \
      const short8 br_ = *reinterpret_cast<const short8*>(Bs + (wn * 16 + l15) * 64 + u_ * 8); \
      _Pragma("unroll")                                                       \
      for (int mi_ = 0; mi_ < 4; ++mi_)                                       \
        ACC_R[mi_] = __builtin_amdgcn_mfma_f32_16x16x32_bf16(af_[mi_], br_, ACC_R[mi_], 0, 0, 0); \
      if (CPLX) {                                                             \
        const short8 bi_ = *reinterpret_cast<const short8*>(Bs + (32 + wn * 16 + l15) * 64 + u_ * 8); \
        _Pragma("unroll")                                                     \
        for (int mi_ = 0; mi_ < 4; ++mi_)                                     \
          ACC_I[mi_] = __builtin_amdgcn_mfma_f32_16x16x32_bf16(af_[mi_], bi_, ACC_I[mi_], 0, 0, 0); \
      }                                                                       \
    }                                                                         \
    __syncthreads();                                                          \
  }

// ---- fused 5-plane GEMM + in-register irfft + bias -> out fp32 ----
// Block: 128 m-rows x 32 out-blocks (256 features). Waves 2x2: wave tile
// 64 m x 16 out-blocks. All planes share (m,outblk) frag indexing, so irfft
// inputs for one output element live in the same lane/reg slot across the 8
// accumulator banks -> epilogue is pure per-thread register math.
__global__ __launch_bounds__(256) void gemm_fused_kernel(
    const unsigned short* __restrict__ XF,
    const unsigned short* __restrict__ WF,
    const float* __restrict__ bias,
    float* __restrict__ out)
{
  // XCD chunking: 1024 blocks, bid&7 = XCD. Chunk = 16 mt x 8 nt: nt-inner
  // (8 consecutive blocks share the 1MB A panel), W chunk ~3.7MB L2-resident
  // across the mt sweep.
  const int bid = blockIdx.x;                // 0..1023
  const int xcd = bid & 7;
  const int idx = bid >> 3;                  // 0..127
  const int mt  = (xcd >> 1) * 16 + (idx >> 3);   // 0..63
  const int nt  = (xcd & 1) * 8 + (idx & 7);      // 0..15
  const int m0  = mt * 128;
  const int n0b = nt * 32;                   // out-block base (32 blocks/tile)

  __shared__ alignas(16) unsigned short As[128 * 64];   // 16 KB
  __shared__ alignas(16) unsigned short Bs[64 * 64];    // 8 KB

  const int tid  = threadIdx.x;
  const int lane = tid & 63;
  const int wave = tid >> 6;
  const int wm   = wave >> 1;
  const int wn   = wave & 1;
  const int quad = lane >> 4;
  const int l15  = lane & 15;
  const int par4 = (l15 & 1) << 2;           // read-side XOR on unit bit 2

  floatx4 a0c[4], a4c[4], c1r[4], c1i[4], c2r[4], c2i[4], c3r[4], c3i[4];
#pragma unroll
  for (int i = 0; i < 4; ++i) {
    a0c[i] = (floatx4){0.f,0.f,0.f,0.f}; a4c[i] = (floatx4){0.f,0.f,0.f,0.f};
    c1r[i] = (floatx4){0.f,0.f,0.f,0.f}; c1i[i] = (floatx4){0.f,0.f,0.f,0.f};
    c2r[i] = (floatx4){0.f,0.f,0.f,0.f}; c2i[i] = (floatx4){0.f,0.f,0.f,0.f};
    c3r[i] = (floatx4){0.f,0.f,0.f,0.f}; c3i[i] = (floatx4){0.f,0.f,0.f,0.f};
  }

  PLANE_LOOP(512,  XF + P0_OFF, WF + Q0_OFF, a0c, a0c, 0)
  PLANE_LOOP(1024, XF + P1_OFF, WF + Q1_OFF, c1r, c1i, 1)
  PLANE_LOOP(1024, XF + P2_OFF, WF + Q2_OFF, c2r, c2i, 1)
  PLANE_LOOP(1024, XF + P3_OFF, WF + Q3_OFF, c3r, c3i, 1)
  PLANE_LOOP(512,  XF + P4_OFF, WF + Q4_OFF, a4c, a4c, 0)

  // epilogue: irfft + bias, fp32 store. col = out-block n0b+wn*16+l15 for
  // ALL (mi,reg); row = m0+wm*64+mi*16+quad*4+reg.
  const int colb = n0b + wn * 16 + l15;      // out-block 0..511
  const f32x4 blo = *reinterpret_cast<const f32x4*>(bias + colb * 8);
  const f32x4 bhi = *reinterpret_cast<const f32x4*>(bias + colb * 8 + 4);

#pragma unroll
  for (int mi = 0; mi < 4; ++mi) {
#pragma unroll
    for (int rg = 0; rg < 4; ++rg) {
      const float a0 = a0c[mi][rg], a4 = a4c[mi][rg];
      const float r1 = c1r[mi][rg], i1 = c1i[mi][rg];
      const float r2 = c2r[mi][rg], i2 = c2i[mi][rg];
      const float r3 = c3r[mi][rg], i3 = c3i[mi][rg];

      const float ep = a0 + a4, em = a0 - a4;
      const float sr1 = SQ2H * r1, si1 = SQ2H * i1;
      const float sr3 = SQ2H * r3, si3 = SQ2H * i3;
      float o[8];
      o[0] = (ep + 2.f * ( r1 + r2 + r3)) * 0.125f;
      o[1] = (em + 2.f * ( sr1 - si1 - i2 - sr3 - si3)) * 0.125f;
      o[2] = (ep + 2.f * (-i1 - r2 + i3)) * 0.125f;
      o[3] = (em + 2.f * (-sr1 - si1 + i2 + sr3 - si3)) * 0.125f;
      o[4] = (ep + 2.f * (-r1 + r2 - r3)) * 0.125f;
      o[5] = (em + 2.f * (-sr1 + si1 - i2 + sr3 + si3)) * 0.125f;
      o[6] = (ep + 2.f * ( i1 - r2 - i3)) * 0.125f;
      o[7] = (em + 2.f * ( sr1 + si1 + i2 - sr3 + si3)) * 0.125f;

      f32x4 lo, hi;
#pragma unroll
      for (int tt = 0; tt < 4; ++tt) { lo[tt] = o[tt] + blo[tt]; hi[tt] = o[tt + 4] + bhi[tt]; }
      const int mrow = m0 + wm * 64 + mi * 16 + quad * 4 + rg;
      float* dst = out + (size_t)mrow * N_DIM + colb * 8;
      *reinterpret_cast<f32x4*>(dst)     = lo;
      *reinterpret_cast<f32x4*>(dst + 4) = hi;
    }
  }
}

// ===========================================================================
// FALLBACK PATH (passing): dense W expansion + one big GEMM
// ===========================================================================

__global__ __launch_bounds__(256) void convert_x_kernel(
    const float* __restrict__ x, unsigned short* __restrict__ Xb)
{
  const size_t t = (size_t)blockIdx.x * 256 + threadIdx.x;
  const f32x4 a = *reinterpret_cast<const f32x4*>(x + t * 8);
  const f32x4 b = *reinterpret_cast<const f32x4*>(x + t * 8 + 4);
  union { u16x8 v; unsigned short s[8]; } o;
#pragma unroll
  for (int u = 0; u < 4; ++u) { o.s[u] = f32_to_bf16(a[u]); o.s[u + 4] = f32_to_bf16(b[u]); }
  *reinterpret_cast<u16x8*>(Xb + t * 8) = o.v;
}

__global__ __launch_bounds__(256) void expand_w_kernel(
    const float* __restrict__ c, unsigned short* __restrict__ W)
{
  const int tid = blockIdx.x * 256 + threadIdx.x;
  const int o = tid >> 9, i = tid & 511, n = o >> 3, t = o & 7;
  const float* src = c + ((size_t)(n * NB + i) << 3);
  float raw[8];
  *reinterpret_cast<f32x4*>(raw)     = *reinterpret_cast<const f32x4*>(src);
  *reinterpret_cast<f32x4*>(raw + 4) = *reinterpret_cast<const f32x4*>(src + 4);
  union { u16x8 v; unsigned short s[8]; } outv;
#pragma unroll
  for (int u = 0; u < 8; ++u) outv.s[u] = f32_to_bf16(raw[(t - u) & 7]);
  *reinterpret_cast<u16x8*>(W + (size_t)o * K_DIM + i * 8) = outv.v;
}

__global__ __launch_bounds__(256) void gemm_bt_kernel(
    const unsigned short* __restrict__ A, const unsigned short* __restrict__ Bm,
    const float* __restrict__ bias, float* __restrict__ C)
{
  __shared__ alignas(16) unsigned short As[128 * 32];
  __shared__ alignas(16) unsigned short Bs[128 * 32];
  const int tid = threadIdx.x, lane = tid & 63, wave = tid >> 6;
  const int wm = wave >> 1, wn = wave & 1;
  const int m0 = blockIdx.y * 128, n0 = blockIdx.x * 128;
  const int quad = lane >> 4, l15 = lane & 15;

  floatx4 acc[4][4];
#pragma unroll
  for (int i = 0; i < 4; ++i)
#pragma unroll
    for (int j = 0; j < 4; ++j) acc[i][j] = (floatx4){0.f, 0.f, 0.f, 0.f};

  for (int k0 = 0; k0 < K_DIM; k0 += 32) {
#pragma unroll
    for (int j = 0; j < 2; ++j) {
      const int chunk = j * 256 + wave * 64 + lane;
      const int row = chunk >> 2, kc = (chunk & 3) << 3;
      const unsigned short* ga = A  + (size_t)(m0 + row) * K_DIM + (k0 + kc);
      const unsigned short* gb = Bm + (size_t)(n0 + row) * K_DIM + (k0 + kc);
      unsigned short* la = As + (j * 256 + wave * 64) * 8;
      unsigned short* lb = Bs + (j * 256 + wave * 64) * 8;
      __builtin_amdgcn_global_load_lds((AS1 void*)ga, (AS3 void*)la, 16, 0, 0);
      __builtin_amdgcn_global_load_lds((AS1 void*)gb, (AS3 void*)lb, 16, 0, 0);
    }
    __syncthreads();
    short8 af[4], bf[4];
#pragma unroll
    for (int mi = 0; mi < 4; ++mi)
      af[mi] = *reinterpret_cast<const short8*>(As + (wm * 64 + mi * 16 + l15) * 32 + quad * 8);
#pragma unroll
    for (int ni = 0; ni < 4; ++ni)
      bf[ni] = *reinterpret_cast<const short8*>(Bs + (wn * 64 + ni * 16 + l15) * 32 + quad * 8);
#pragma unroll
    for (int mi = 0; mi < 4; ++mi)
#pragma unroll
      for (int ni = 0; ni < 4; ++ni)
        acc[mi][ni] = __builtin_amdgcn_mfma_f32_16x16x32_bf16(af[mi], bf[ni], acc[mi][ni], 0, 0, 0);
    __syncthreads();
  }
  float bv[4]; int cols[4];
#pragma unroll
  for (int ni = 0; ni < 4; ++ni) { cols[ni] = n0 + wn * 64 + ni * 16 + l15; bv[ni] = bias[cols[ni]]; }
#pragma unroll
  for (int mi = 0; mi < 4; ++mi)
#pragma unroll
    for (int r = 0; r < 4; ++r) {
      const int grow = m0 + wm * 64 + mi * 16 + quad * 4 + r;
      float* crow = C + (size_t)grow * N_DIM;
#pragma unroll
      for (int ni = 0; ni < 4; ++ni) crow[cols[ni]] = acc[mi][ni][r] + bv[ni];
    }
}

extern "C" void kernel_launch(void* const* d_in, const int* in_sizes, int n_in,
                              void* d_out, int out_size, void* d_ws, size_t ws_size,
                              hipStream_t stream) {
  const float* x    = (const float*)d_in[0];
  const float* circ = (const float*)d_in[1];
  const float* bias = (const float*)d_in[2];
  float* out = (float*)d_out;

  // freq-domain ws layout: XF bf16 64MB | WF bf16 7MB (OF eliminated)
  const size_t XF_BYTES = (size_t)33554432 * 2;
  const size_t WF_BYTES = (size_t)3670016 * 2;
  const size_t NEED = XF_BYTES + WF_BYTES;   // 74,448,896 B

  if (ws_size >= NEED) {
    unsigned short* XF = (unsigned short*)d_ws;
    unsigned short* WF = (unsigned short*)((char*)d_ws + XF_BYTES);

    prep_kernel<<<1024 + M_DIM / 2, 256, 0, stream>>>(x, circ, XF, WF);
    gemm_fused_kernel<<<1024, 256, 0, stream>>>(XF, WF, bias, out);
  } else {
    // fallback: dense GEMM path (96 MB ws)
    unsigned short* W  = (unsigned short*)d_ws;
    unsigned short* Xb = (unsigned short*)((char*)d_ws + (size_t)N_DIM * K_DIM * 2);
    convert_x_kernel<<<(M_DIM * K_DIM / 8) / 256, 256, 0, stream>>>(x, Xb);
    expand_w_kernel<<<(N_DIM * NB) / 256, 256, 0, stream>>>(circ, W);
    dim3 grid(N_DIM / 128, M_DIM / 128);
    gemm_bt_kernel<<<grid, 256, 0, stream>>>(Xb, W, bias, out);
  }
}

// Round 5
// 348.204 us; speedup vs baseline: 1.3561x; 1.3561x over previous
//
#include <hip/hip_runtime.h>

#define AS1 __attribute__((address_space(1)))
#define AS3 __attribute__((address_space(3)))

typedef __attribute__((ext_vector_type(8))) short short8;        // 8 bf16 raw (4 VGPRs) — MFMA A/B frag
typedef __attribute__((ext_vector_type(4))) float floatx4;       // MFMA C/D frag
typedef __attribute__((ext_vector_type(8))) unsigned short u16x8;
typedef __attribute__((ext_vector_type(4))) unsigned short u16x4;
typedef __attribute__((ext_vector_type(4))) float f32x4;

#define M_DIM 8192   // B*S = 4*2048
#define K_DIM 4096   // IN_F
#define N_DIM 4096   // OUT_F
#define NB    512    // blocks along in/out feature dims
// BLK = 8, rfft comps: f0(real), f1,f2,f3(complex), f4(real)

#define SQ2H 0.70710678118654752f

// Xfreq / Ofreq plane offsets (bf16 elements), total 33,554,432 elems = 64 MB
#define P0_OFF 0           // [8192][512]  f0 (real)
#define P1_OFF 4194304     // [8192][1024] f1 (re,im interleaved k=2i,2i+1)
#define P2_OFF 12582912    // [8192][1024] f2
#define P3_OFF 20971520    // [8192][1024] f3
#define P4_OFF 29360128    // [8192][512]  f4 (real)
// Wfreq plane offsets (bf16 elements), total 3,670,016 elems = 7 MB
#define Q0_OFF 0           // [512][512]
#define Q1_OFF 262144      // [1024][1024] rows 0..511: (B1r,-B1i); rows 512..1023: (B1i,B1r)
#define Q2_OFF 1310720
#define Q3_OFF 2359296
#define Q4_OFF 3407872     // [512][512]

// fp32 -> bf16 raw bits, round-to-nearest-even (finite inputs only).
static __device__ __forceinline__ unsigned short f32_to_bf16(float f) {
  union { float f; unsigned int u; } v;
  v.f = f;
  return (unsigned short)((v.u + 0x7FFFu + ((v.u >> 16) & 1u)) >> 16);
}
static __device__ __forceinline__ float bf16_to_f32(unsigned short h) {
  union { unsigned int u; float f; } v;
  v.u = ((unsigned int)h) << 16;
  return v.f;
}

// length-8 real FFT comps from 8 reals
struct F8 { float a0, a4, r1, i1, r2, i2, r3, i3; };
static __device__ __forceinline__ F8 rfft8(const float* x) {
  F8 o;
  o.a0 = x[0]+x[1]+x[2]+x[3]+x[4]+x[5]+x[6]+x[7];
  o.a4 = x[0]-x[1]+x[2]-x[3]+x[4]-x[5]+x[6]-x[7];
  const float d1 = x[1]-x[3]-x[5]+x[7];   // for r1/r3
  const float s1 = x[1]+x[3]-x[5]-x[7];   // for i1/i3
  o.r1 = x[0]-x[4] + SQ2H*d1;
  o.i1 = -(SQ2H*s1 + x[2]-x[6]);
  o.r2 = x[0]-x[2]+x[4]-x[6];
  o.i2 = -(x[1]-x[3]+x[5]-x[7]);
  o.r3 = x[0]-x[4] - SQ2H*d1;
  o.i3 = -(SQ2H*s1 - x[2]+x[6]);
  return o;
}

// ===========================================================================
// FREQ PATH, 3 kernels: prep (w+x fused) -> per-plane GEMM (dbuf) -> irfft
// ===========================================================================

// blocks [0,1024): circ -> WF.  blocks [1024,1024+4096): x -> XF (LDS-bounce).
__global__ __launch_bounds__(256) void prep_kernel(
    const float* __restrict__ x, const float* __restrict__ circ,
    unsigned short* __restrict__ XF, unsigned short* __restrict__ WF)
{
  __shared__ alignas(16) float lds[8192];          // 32 KB (x-branch only)
  const int t = threadIdx.x;

  if (blockIdx.x < 1024) {
    // ---- wtransform: circ (fp32 (512,512,8)) -> Wfreq planes (bf16) ----
    const int tid = blockIdx.x * 256 + t;          // 0 .. 512*512-1
    const int n = tid >> 9;   // output block
    const int i = tid & 511;  // input block
    float v[8];
    *reinterpret_cast<f32x4*>(v)     = *reinterpret_cast<const f32x4*>(circ + (size_t)tid * 8);
    *reinterpret_cast<f32x4*>(v + 4) = *reinterpret_cast<const f32x4*>(circ + (size_t)tid * 8 + 4);
    F8 f = rfft8(v);
    WF[Q0_OFF + (size_t)n * 512 + i] = f32_to_bf16(f.a0);
    WF[Q4_OFF + (size_t)n * 512 + i] = f32_to_bf16(f.a4);
    unsigned int q1or = (unsigned int)f32_to_bf16(f.r1) | ((unsigned int)f32_to_bf16(-f.i1) << 16);
    unsigned int q1oi = (unsigned int)f32_to_bf16(f.i1) | ((unsigned int)f32_to_bf16(f.r1) << 16);
    unsigned int q2or = (unsigned int)f32_to_bf16(f.r2) | ((unsigned int)f32_to_bf16(-f.i2) << 16);
    unsigned int q2oi = (unsigned int)f32_to_bf16(f.i2) | ((unsigned int)f32_to_bf16(f.r2) << 16);
    unsigned int q3or = (unsigned int)f32_to_bf16(f.r3) | ((unsigned int)f32_to_bf16(-f.i3) << 16);
    unsigned int q3oi = (unsigned int)f32_to_bf16(f.i3) | ((unsigned int)f32_to_bf16(f.r3) << 16);
    *reinterpret_cast<unsigned int*>(WF + Q1_OFF + (size_t)n * 1024 + 2 * i)         = q1or;
    *reinterpret_cast<unsigned int*>(WF + Q1_OFF + (size_t)(512 + n) * 1024 + 2 * i) = q1oi;
    *reinterpret_cast<unsigned int*>(WF + Q2_OFF + (size_t)n * 1024 + 2 * i)         = q2or;
    *reinterpret_cast<unsigned int*>(WF + Q2_OFF + (size_t)(512 + n) * 1024 + 2 * i) = q2oi;
    *reinterpret_cast<unsigned int*>(WF + Q3_OFF + (size_t)n * 1024 + 2 * i)         = q3or;
    *reinterpret_cast<unsigned int*>(WF + Q3_OFF + (size_t)(512 + n) * 1024 + 2 * i) = q3oi;
    return;
  }

  // ---- xtransform: x (fp32 (8192,4096)) -> Xfreq planes, LDS-bounce ----
  const int bx = blockIdx.x - 1024;                // 0..4095
  const int m0 = bx * 2;
  const float* src = x + (size_t)m0 * 4096;

#pragma unroll
  for (int s = 0; s < 8; ++s) {
    const int u  = s * 256 + t;                    // 16B-unit 0..2047
    const int pu = u ^ ((u >> 3) & 7);
    *reinterpret_cast<f32x4*>(lds + pu * 4) =
        *reinterpret_cast<const f32x4*>(src + (size_t)u * 4);
  }
  __syncthreads();

  const int r  = t >> 7;                           // local row 0/1
  const int i4 = t & 127;                          // input blocks i4*4 .. +3
  float v[32];
#pragma unroll
  for (int p = 0; p < 8; ++p) {
    const int u  = r * 1024 + i4 * 8 + p;
    const int pu = u ^ ((u >> 3) & 7);
    *reinterpret_cast<f32x4*>(v + p * 4) = *reinterpret_cast<const f32x4*>(lds + pu * 4);
  }

  const int m = m0 + r;
  u16x4 p0, p4;
  u16x8 p1, p2, p3;
#pragma unroll
  for (int g = 0; g < 4; ++g) {
    F8 f = rfft8(v + g * 8);
    p0[g] = f32_to_bf16(f.a0);
    p4[g] = f32_to_bf16(f.a4);
    p1[2*g] = f32_to_bf16(f.r1); p1[2*g+1] = f32_to_bf16(f.i1);
    p2[2*g] = f32_to_bf16(f.r2); p2[2*g+1] = f32_to_bf16(f.i2);
    p3[2*g] = f32_to_bf16(f.r3); p3[2*g+1] = f32_to_bf16(f.i3);
  }
  *reinterpret_cast<u16x4*>(XF + P0_OFF + (size_t)m * 512 + i4 * 4) = p0;
  *reinterpret_cast<u16x4*>(XF + P4_OFF + (size_t)m * 512 + i4 * 4) = p4;
  *reinterpret_cast<u16x8*>(XF + P1_OFF + (size_t)m * 1024 + i4 * 8) = p1;
  *reinterpret_cast<u16x8*>(XF + P2_OFF + (size_t)m * 1024 + i4 * 8) = p2;
  *reinterpret_cast<u16x8*>(XF + P3_OFF + (size_t)m * 1024 + i4 * 8) = p3;
}

// ---- per-frequency GEMM: O_z(M,Nz) = X_z(M,Kz) * W_z(Nz,Kz)^T, bf16 ----
// 128x128 tile, BK=32, DOUBLE-BUFFERED single-barrier K-loop: STAGE(next)
// issued before COMPUTE(cur) so the __syncthreads vmcnt-drain lands after a
// full 16-MFMA phase. Proper both-sides swizzle: 16B-unit ^= (row>>1)&3
// (staging pre-swizzles the GLOBAL source unit, gload_lds dest linear; read
// applies the same XOR) -> max 2-way bank aliasing (free).
#define STAGE(AsB, BsB, step)                                                 \
  {                                                                           \
    const int kk_ = (step) * 32;                                              \
    _Pragma("unroll")                                                         \
    for (int j_ = 0; j_ < 2; ++j_) {                                          \
      const int c_   = j_ * 256 + tid;           /* 0..511 */                 \
      const int row_ = c_ >> 2;                  /* 0..127 */                 \
      const int lu_  = (c_ & 3) ^ ((row_ >> 1) & 3);                          \
      const unsigned short* ga_ = A  + (size_t)(m0 + row_) * K + kk_ + lu_ * 8; \
      const unsigned short* gb_ = Bm + (size_t)(n0 + row_) * K + kk_ + lu_ * 8; \
      __builtin_amdgcn_global_load_lds((AS1 void*)ga_, (AS3 void*)((AsB) + c_ * 8), 16, 0, 0); \
      __builtin_amdgcn_global_load_lds((AS1 void*)gb_, (AS3 void*)((BsB) + c_ * 8), 16, 0, 0); \
    }                                                                         \
  }

#define COMPUTE(AsB, BsB)                                                     \
  {                                                                           \
    short8 af_[4], bf_[4];                                                    \
    _Pragma("unroll")                                                         \
    for (int mi_ = 0; mi_ < 4; ++mi_)                                         \
      af_[mi_] = *reinterpret_cast<const short8*>((AsB) + (wm * 64 + mi_ * 16 + l15) * 32 + ua * 8); \
    _Pragma("unroll")                                                         \
    for (int ni_ = 0; ni_ < 4; ++ni_)                                         \
      bf_[ni_] = *reinterpret_cast<const short8*>((BsB) + (wn * 64 + ni_ * 16 + l15) * 32 + ua * 8); \
    _Pragma("unroll")                                                         \
    for (int mi_ = 0; mi_ < 4; ++mi_)                                         \
      _Pragma("unroll")                                                       \
      for (int ni_ = 0; ni_ < 4; ++ni_)                                       \
        acc[mi_][ni_] = __builtin_amdgcn_mfma_f32_16x16x32_bf16(af_[mi_], bf_[ni_], acc[mi_][ni_], 0, 0, 0); \
  }

__global__ __launch_bounds__(256) void gemm_freq_kernel(
    const unsigned short* __restrict__ XF,
    const unsigned short* __restrict__ WF,
    unsigned short* __restrict__ OF)
{
  const int bid = blockIdx.x;                 // 0..2047, 2048 % 8 == 0 -> bijective
  const int swz = (bid & 7) * 256 + (bid >> 3);
  const int mt  = swz >> 5;                   // 0..63  (m-tile, outer)
  const int yf  = swz & 31;                   // 0..31  (flattened (z, n-tile))
  int z, nt;
  if (yf < 4)       { z = 0; nt = yf; }
  else if (yf < 28) { z = 1 + ((yf - 4) >> 3); nt = (yf - 4) & 7; }
  else              { z = 4; nt = yf - 28; }

  int K, aoff, boff;  // N == K for every plane; O plane offset == A plane offset
  switch (z) {
    case 0:  K = 512;  aoff = P0_OFF; boff = Q0_OFF; break;
    case 1:  K = 1024; aoff = P1_OFF; boff = Q1_OFF; break;
    case 2:  K = 1024; aoff = P2_OFF; boff = Q2_OFF; break;
    case 3:  K = 1024; aoff = P3_OFF; boff = Q3_OFF; break;
    default: K = 512;  aoff = P4_OFF; boff = Q4_OFF; break;
  }
  const int n0 = nt * 128;
  const int m0 = mt * 128;

  const unsigned short* A  = XF + aoff;
  const unsigned short* Bm = WF + boff;
  unsigned short* C        = OF + aoff;

  __shared__ alignas(16) unsigned short As0[128 * 32];   // 4 x 8 KB = 32 KB
  __shared__ alignas(16) unsigned short Bs0[128 * 32];
  __shared__ alignas(16) unsigned short As1[128 * 32];
  __shared__ alignas(16) unsigned short Bs1[128 * 32];

  const int tid  = threadIdx.x;
  const int lane = tid & 63;
  const int wave = tid >> 6;
  const int wm   = wave >> 1;
  const int wn   = wave & 1;
  const int quad = lane >> 4;
  const int l15  = lane & 15;
  const int ua   = quad ^ ((l15 >> 1) & 3);   // read-side swizzled 16B-unit

  floatx4 acc[4][4];
#pragma unroll
  for (int i = 0; i < 4; ++i)
#pragma unroll
    for (int j = 0; j < 4; ++j) acc[i][j] = (floatx4){0.f, 0.f, 0.f, 0.f};

  STAGE(As0, Bs0, 0);
  __syncthreads();                            // implicit vmcnt(0) drain

  const int nsteps = K >> 5;                  // 16 or 32, always even
  for (int t = 0; t < nsteps; t += 2) {
    STAGE(As1, Bs1, t + 1);
    COMPUTE(As0, Bs0);
    __syncthreads();
    if (t + 2 < nsteps) STAGE(As0, Bs0, t + 2);
    COMPUTE(As1, Bs1);
    __syncthreads();
  }

  // epilogue: C/D layout col=lane&15, row=quad*4+reg; bf16 store
#pragma unroll
  for (int mi = 0; mi < 4; ++mi) {
#pragma unroll
    for (int r = 0; r < 4; ++r) {
      const int grow = m0 + wm * 64 + mi * 16 + quad * 4 + r;
      unsigned short* crow = C + (size_t)grow * K;
#pragma unroll
      for (int ni = 0; ni < 4; ++ni)
        crow[n0 + wn * 64 + ni * 16 + l15] = f32_to_bf16(acc[mi][ni][r]);
    }
  }
}

// ---- irfft + bias: Ofreq planes (bf16) -> out (fp32 (8192,4096)) ----
__global__ __launch_bounds__(256) void irfft_kernel(
    const unsigned short* __restrict__ OF,
    const float* __restrict__ bias,
    float* __restrict__ out)
{
  __shared__ alignas(16) float lds[256 * 36];        // 36 KB, 144B/row
  const int t   = threadIdx.x;
  const int gt  = blockIdx.x * 256 + t;              // 0 .. 8192*128-1
  const int m   = gt >> 7;
  const int nb4 = gt & 127;                          // blocks nb4*4 .. +3

  const u16x4 a0v = *reinterpret_cast<const u16x4*>(OF + P0_OFF + (size_t)m * 512 + nb4 * 4);
  const u16x4 a4v = *reinterpret_cast<const u16x4*>(OF + P4_OFF + (size_t)m * 512 + nb4 * 4);
  const u16x4 r1v = *reinterpret_cast<const u16x4*>(OF + P1_OFF + (size_t)m * 1024 + nb4 * 4);
  const u16x4 i1v = *reinterpret_cast<const u16x4*>(OF + P1_OFF + (size_t)m * 1024 + 512 + nb4 * 4);
  const u16x4 r2v = *reinterpret_cast<const u16x4*>(OF + P2_OFF + (size_t)m * 1024 + nb4 * 4);
  const u16x4 i2v = *reinterpret_cast<const u16x4*>(OF + P2_OFF + (size_t)m * 1024 + 512 + nb4 * 4);
  const u16x4 r3v = *reinterpret_cast<const u16x4*>(OF + P3_OFF + (size_t)m * 1024 + nb4 * 4);
  const u16x4 i3v = *reinterpret_cast<const u16x4*>(OF + P3_OFF + (size_t)m * 1024 + 512 + nb4 * 4);

  float res[32];
#pragma unroll
  for (int j = 0; j < 4; ++j) {
    const int nblk = nb4 * 4 + j;
    const float a0 = bf16_to_f32(a0v[j]), a4 = bf16_to_f32(a4v[j]);
    const float r1 = bf16_to_f32(r1v[j]), i1 = bf16_to_f32(i1v[j]);
    const float r2 = bf16_to_f32(r2v[j]), i2 = bf16_to_f32(i2v[j]);
    const float r3 = bf16_to_f32(r3v[j]), i3 = bf16_to_f32(i3v[j]);

    const float ep = a0 + a4, em = a0 - a4;
    const float sr1 = SQ2H * r1, si1 = SQ2H * i1;
    const float sr3 = SQ2H * r3, si3 = SQ2H * i3;
    float o[8];
    o[0] = (ep + 2.f * ( r1 + r2 + r3)) * 0.125f;
    o[1] = (em + 2.f * ( sr1 - si1 - i2 - sr3 - si3)) * 0.125f;
    o[2] = (ep + 2.f * (-i1 - r2 + i3)) * 0.125f;
    o[3] = (em + 2.f * (-sr1 - si1 + i2 + sr3 - si3)) * 0.125f;
    o[4] = (ep + 2.f * (-r1 + r2 - r3)) * 0.125f;
    o[5] = (em + 2.f * (-sr1 + si1 - i2 + sr3 + si3)) * 0.125f;
    o[6] = (ep + 2.f * ( i1 - r2 - i3)) * 0.125f;
    o[7] = (em + 2.f * ( sr1 + si1 + i2 - sr3 + si3)) * 0.125f;

    const f32x4 blo = *reinterpret_cast<const f32x4*>(bias + nblk * 8);
    const f32x4 bhi = *reinterpret_cast<const f32x4*>(bias + nblk * 8 + 4);
#pragma unroll
    for (int k = 0; k < 4; ++k) {
      res[j * 8 + k]     = o[k]     + blo[k];
      res[j * 8 + 4 + k] = o[k + 4] + bhi[k];
    }
  }

  // stage to LDS: thread t owns bytes [t*144, t*144+128)
  float* dst = lds + t * 36;
#pragma unroll
  for (int p = 0; p < 8; ++p)
    *reinterpret_cast<f32x4*>(dst + p * 4) = *reinterpret_cast<const f32x4*>(res + p * 4);
  __syncthreads();

  // cooperative coalesced store of the block's 32KB contiguous region
  float* gbase = out + (size_t)blockIdx.x * 8192;    // 2 rows of 4096 floats
#pragma unroll
  for (int s = 0; s < 8; ++s) {
    const int off16 = s * 256 + t;                   // 16B-unit index 0..2047
    const f32x4 vv = *reinterpret_cast<const f32x4*>(
        lds + (off16 >> 3) * 36 + (off16 & 7) * 4);
    *reinterpret_cast<f32x4*>(gbase + off16 * 4) = vv;
  }
}

// ===========================================================================
// FALLBACK PATH (passing): dense W expansion + one big GEMM
// ===========================================================================

__global__ __launch_bounds__(256) void convert_x_kernel(
    const float* __restrict__ x, unsigned short* __restrict__ Xb)
{
  const size_t t = (size_t)blockIdx.x * 256 + threadIdx.x;
  const f32x4 a = *reinterpret_cast<const f32x4*>(x + t * 8);
  const f32x4 b = *reinterpret_cast<const f32x4*>(x + t * 8 + 4);
  union { u16x8 v; unsigned short s[8]; } o;
#pragma unroll
  for (int u = 0; u < 4; ++u) { o.s[u] = f32_to_bf16(a[u]); o.s[u + 4] = f32_to_bf16(b[u]); }
  *reinterpret_cast<u16x8*>(Xb + t * 8) = o.v;
}

__global__ __launch_bounds__(256) void expand_w_kernel(
    const float* __restrict__ c, unsigned short* __restrict__ W)
{
  const int tid = blockIdx.x * 256 + threadIdx.x;
  const int o = tid >> 9, i = tid & 511, n = o >> 3, t = o & 7;
  const float* src = c + ((size_t)(n * NB + i) << 3);
  float raw[8];
  *reinterpret_cast<f32x4*>(raw)     = *reinterpret_cast<const f32x4*>(src);
  *reinterpret_cast<f32x4*>(raw + 4) = *reinterpret_cast<const f32x4*>(src + 4);
  union { u16x8 v; unsigned short s[8]; } outv;
#pragma unroll
  for (int u = 0; u < 8; ++u) outv.s[u] = f32_to_bf16(raw[(t - u) & 7]);
  *reinterpret_cast<u16x8*>(W + (size_t)o * K_DIM + i * 8) = outv.v;
}

__global__ __launch_bounds__(256) void gemm_bt_kernel(
    const unsigned short* __restrict__ A, const unsigned short* __restrict__ Bm,
    const float* __restrict__ bias, float* __restrict__ C)
{
  __shared__ alignas(16) unsigned short As[128 * 32];
  __shared__ alignas(16) unsigned short Bs[128 * 32];
  const int tid = threadIdx.x, lane = tid & 63, wave = tid >> 6;
  const int wm = wave >> 1, wn = wave & 1;
  const int m0 = blockIdx.y * 128, n0 = blockIdx.x * 128;
  const int quad = lane >> 4, l15 = lane & 15;

  floatx4 acc[4][4];
#pragma unroll
  for (int i = 0; i < 4; ++i)
#pragma unroll
    for (int j = 0; j < 4; ++j) acc[i][j] = (floatx4){0.f, 0.f, 0.f, 0.f};

  for (int k0 = 0; k0 < K_DIM; k0 += 32) {
#pragma unroll
    for (int j = 0; j < 2; ++j) {
      const int chunk = j * 256 + wave * 64 + lane;
      const int row = chunk >> 2, kc = (chunk & 3) << 3;
      const unsigned short* ga = A  + (size_t)(m0 + row) * K_DIM + (k0 + kc);
      const unsigned short* gb = Bm + (size_t)(n0 + row) * K_DIM + (k0 + kc);
      unsigned short* la = As + (j * 256 + wave * 64) * 8;
      unsigned short* lb = Bs + (j * 256 + wave * 64) * 8;
      __builtin_amdgcn_global_load_lds((AS1 void*)ga, (AS3 void*)la, 16, 0, 0);
      __builtin_amdgcn_global_load_lds((AS1 void*)gb, (AS3 void*)lb, 16, 0, 0);
    }
    __syncthreads();
    short8 af[4], bf[4];
#pragma unroll
    for (int mi = 0; mi < 4; ++mi)
      af[mi] = *reinterpret_cast<const short8*>(As + (wm * 64 + mi * 16 + l15) * 32 + quad * 8);
#pragma unroll
    for (int ni = 0; ni < 4; ++ni)
      bf[ni] = *reinterpret_cast<const short8*>(Bs + (wn * 64 + ni * 16 + l15) * 32 + quad * 8);
#pragma unroll
    for (int mi = 0; mi < 4; ++mi)
#pragma unroll
      for (int ni = 0; ni < 4; ++ni)
        acc[mi][ni] = __builtin_amdgcn_mfma_f32_16x16x32_bf16(af[mi], bf[ni], acc[mi][ni], 0, 0, 0);
    __syncthreads();
  }
  float bv[4]; int cols[4];
#pragma unroll
  for (int ni = 0; ni < 4; ++ni) { cols[ni] = n0 + wn * 64 + ni * 16 + l15; bv[ni] = bias[cols[ni]]; }
#pragma unroll
  for (int mi = 0; mi < 4; ++mi)
#pragma unroll
    for (int r = 0; r < 4; ++r) {
      const int grow = m0 + wm * 64 + mi * 16 + quad * 4 + r;
      float* crow = C + (size_t)grow * N_DIM;
#pragma unroll
      for (int ni = 0; ni < 4; ++ni) crow[cols[ni]] = acc[mi][ni][r] + bv[ni];
    }
}

extern "C" void kernel_launch(void* const* d_in, const int* in_sizes, int n_in,
                              void* d_out, int out_size, void* d_ws, size_t ws_size,
                              hipStream_t stream) {
  const float* x    = (const float*)d_in[0];
  const float* circ = (const float*)d_in[1];
  const float* bias = (const float*)d_in[2];
  float* out = (float*)d_out;

  // freq-domain ws layout: XF bf16 64MB | WF bf16 7MB | OF bf16 64MB
  const size_t XF_BYTES = (size_t)33554432 * 2;
  const size_t WF_BYTES = (size_t)3670016 * 2;
  const size_t OF_BYTES = (size_t)33554432 * 2;
  const size_t NEED = XF_BYTES + WF_BYTES + OF_BYTES;  // 141,557,760 B

  if (ws_size >= NEED) {
    unsigned short* XF = (unsigned short*)d_ws;
    unsigned short* WF = (unsigned short*)((char*)d_ws + XF_BYTES);
    unsigned short* OF = (unsigned short*)((char*)d_ws + XF_BYTES + WF_BYTES);

    prep_kernel<<<1024 + M_DIM / 2, 256, 0, stream>>>(x, circ, XF, WF);
    gemm_freq_kernel<<<2048, 256, 0, stream>>>(XF, WF, OF);
    irfft_kernel<<<M_DIM / 2, 256, 0, stream>>>(OF, bias, out);
  } else {
    // fallback: dense GEMM path (96 MB ws)
    unsigned short* W  = (unsigned short*)d_ws;
    unsigned short* Xb = (unsigned short*)((char*)d_ws + (size_t)N_DIM * K_DIM * 2);
    convert_x_kernel<<<(M_DIM * K_DIM / 8) / 256, 256, 0, stream>>>(x, Xb);
    expand_w_kernel<<<(N_DIM * NB) / 256, 256, 0, stream>>>(circ, W);
    dim3 grid(N_DIM / 128, M_DIM / 128);
    gemm_bt_kernel<<<grid, 256, 0, stream>>>(Xb, W, bias, out);
  }
}